// Round 9
// baseline (435.555 us; speedup 1.0000x reference)
//
#include <hip/hip_runtime.h>

#define TT 8192
#define HH 2048
#define II 768
#define NE 16
#define TOPK 2
#define CAP 16384

typedef float f32x4 __attribute__((ext_vector_type(4)));
typedef float f32x8 __attribute__((ext_vector_type(8)));
typedef short bf16x8 __attribute__((ext_vector_type(8)));
typedef unsigned short ushort8 __attribute__((ext_vector_type(8)));

__device__ __forceinline__ unsigned short f2bf(float f) {
    unsigned u = __builtin_bit_cast(unsigned, f);
    u += 0x7fffu + ((u >> 16) & 1u);
    return (unsigned short)(u >> 16);
}

__device__ __forceinline__ float bf2f(unsigned short u) {
    return __builtin_bit_cast(float, (unsigned)u << 16);
}

__device__ __forceinline__ void glds16(const void* g, void* l) {
    __builtin_amdgcn_global_load_lds((const __attribute__((address_space(1))) void*)g,
                                     (__attribute__((address_space(3))) void*)l, 16, 0, 0);
}

// ---------------- merged cast: wg1 tiles | wg2 tiles | hs bf16 ----------------
__global__ void cast_all_kernel(const float* __restrict__ gup, const float* __restrict__ dwn,
                                const float* __restrict__ hs,
                                unsigned short* __restrict__ wg1, unsigned short* __restrict__ wg2,
                                unsigned short* __restrict__ hsb) {
    const int bid = blockIdx.x;
    if (bid < 24576) {
        size_t gid = (size_t)bid * 256 + threadIdx.x;  // 6,291,456 chunks
        int sc = gid & 7;
        int r = (gid >> 3) & 255;
        int kt = (gid >> 11) & 31;
        int rest = (int)(gid >> 16);      // e*6 + it
        int it = rest % 6;
        int e = rest / 6;
        int chunk = sc ^ (r & 7);
        int grow = (r < 128) ? (it * 128 + r) : (II + it * 128 + (r - 128));
        const float4* s = reinterpret_cast<const float4*>(
            &gup[((size_t)e * (2 * II) + grow) * HH + kt * 64 + chunk * 8]);
        float4 v0 = s[0], v1 = s[1];
        ushort8 o;
        o[0] = f2bf(v0.x); o[1] = f2bf(v0.y); o[2] = f2bf(v0.z); o[3] = f2bf(v0.w);
        o[4] = f2bf(v1.x); o[5] = f2bf(v1.y); o[6] = f2bf(v1.z); o[7] = f2bf(v1.w);
        *reinterpret_cast<ushort8*>(&wg1[gid * 8]) = o;
    } else if (bid < 36864) {
        size_t gid = (size_t)(bid - 24576) * 256 + threadIdx.x;  // 3,145,728 chunks
        int sc = gid & 7;
        int r = (gid >> 3) & 127;
        int kt = (int)((gid >> 10) % 12);
        int rest = (int)(gid / (12 << 10));  // e*16 + ht
        int ht = rest & 15;
        int e = rest >> 4;
        int chunk = sc ^ (r & 7);
        int hrow = ht * 128 + r;
        const float4* s = reinterpret_cast<const float4*>(
            &dwn[((size_t)e * HH + hrow) * II + kt * 64 + chunk * 8]);
        float4 v0 = s[0], v1 = s[1];
        ushort8 o;
        o[0] = f2bf(v0.x); o[1] = f2bf(v0.y); o[2] = f2bf(v0.z); o[3] = f2bf(v0.w);
        o[4] = f2bf(v1.x); o[5] = f2bf(v1.y); o[6] = f2bf(v1.z); o[7] = f2bf(v1.w);
        *reinterpret_cast<ushort8*>(&wg2[gid * 8]) = o;
    } else {
        int i = (bid - 36864) * 256 + threadIdx.x;  // float4 chunks of hs
        const float4 v = reinterpret_cast<const float4*>(hs)[i];
        ushort4 o;
        o.x = f2bf(v.x); o.y = f2bf(v.y); o.z = f2bf(v.z); o.w = f2bf(v.w);
        reinterpret_cast<ushort4*>(hsb)[i] = o;
    }
}

// ---------------- routing (packs k-slot into bit 15 of tok entry) ----------------
__global__ void route_kernel(const int* __restrict__ idx, const float* __restrict__ w,
                             int* __restrict__ counts, int* __restrict__ toks,
                             float* __restrict__ wts) {
    int t = blockIdx.x * blockDim.x + threadIdx.x;
    if (t >= TT) return;
    #pragma unroll
    for (int k = 0; k < TOPK; ++k) {
        int e = idx[t * TOPK + k];
        int p = atomicAdd(&counts[e], 1);
        toks[e * CAP + p] = t | (k << 15);
        wts[e * CAP + p] = w[t * TOPK + k];
    }
}

__global__ void scan_kernel(const int* __restrict__ counts, int* __restrict__ poffs,
                            int* __restrict__ ntot, int* __restrict__ tmap) {
    if (threadIdx.x == 0) {
        int s = 0, nt = 0;
        for (int e = 0; e < NE; ++e) {
            poffs[e] = s;
            int ct = (counts[e] + 127) >> 7;
            for (int m = 0; m < ct; ++m) tmap[nt++] = e | (m << 8);
            s += ct << 7;
        }
        poffs[NE] = s;
        ntot[0] = nt;
    }
}

// ---------------- GEMM1: 128x(128g+128u) tile, 512 thr, counted-vmcnt dbuf ----------------
// T4 pipeline: STAGE(kt+2) after read-done barrier, s_waitcnt vmcnt(6) (waits
// tile kt+1 only, kt+2 stays in flight), raw s_barrier. Never vmcnt(0) in
// steady state. 8 waves/CU (R7 lesson: 4 waves/CU = cliff).
__global__ __launch_bounds__(512) void gemm1_kernel(
    const unsigned short* __restrict__ hsb, const unsigned short* __restrict__ wg1,
    const int* __restrict__ counts, const int* __restrict__ poffs,
    const int* __restrict__ ntotp, const int* __restrict__ tmap,
    const int* __restrict__ toks, unsigned short* __restrict__ actT) {
    const int b = blockIdx.x;                 // 864 = 6*144
    const int w = (b & 7) * 108 + (b >> 3);   // XCD-grouped
    const int ibt = w / 144;                  // i-tile 0..5
    const int gt = w % 144;
    if (gt >= ntotp[0]) return;
    const int ent = tmap[gt];
    const int e = ent & 255;
    const int mbase = (ent >> 8) << 7;
    const int cnt = counts[e];
    const int tid = threadIdx.x;
    const int lane = tid & 63;
    const int wid = tid >> 6;   // 0..7
    const int wm = wid >> 2;    // 0..1
    const int wn = wid & 3;     // 0..3

    __shared__ unsigned short sA0[128 * 64], sA1[128 * 64];   // 16 KB each
    __shared__ unsigned short sB0[256 * 64], sB1[256 * 64];   // 32 KB each
    __shared__ int s_tok[128];

    if (tid < 128) {
        int r = mbase + tid;
        s_tok[tid] = toks[e * CAP + ((r < cnt) ? r : (cnt - 1))] & 0x1FFF;
    }
    __syncthreads();   // also drains vmcnt -> clean counter base for the pipeline

    size_t abase[2];
    #pragma unroll
    for (int it = 0; it < 2; ++it) {
        int idx = it * 512 + tid;
        int r = idx >> 3, sc = idx & 7;
        abase[it] = (size_t)s_tok[r] * HH + ((sc ^ (r & 7)) << 3);
    }
    const unsigned short* bbase = wg1 + ((size_t)(e * 6 + ibt) << 19) + (size_t)tid * 8;

    f32x4 accg[4][2], accu[4][2];
    #pragma unroll
    for (int m = 0; m < 4; ++m)
        #pragma unroll
        for (int n = 0; n < 2; ++n) {
            accg[m][n] = (f32x4){0.f, 0.f, 0.f, 0.f};
            accu[m][n] = (f32x4){0.f, 0.f, 0.f, 0.f};
        }

    const int lrow = lane & 15;
    const int lk8 = (lane >> 4) << 3;

#define G1_STAGE(SA, SB, kt) do {                                              \
    _Pragma("unroll")                                                          \
    for (int it = 0; it < 2; ++it)                                             \
        glds16(hsb + abase[it] + (size_t)(kt) * 64,                            \
               (char*)(SA) + it * 8192 + wid * 1024);                          \
    const unsigned short* bk_ = bbase + (size_t)(kt) * 16384;                  \
    _Pragma("unroll")                                                          \
    for (int it = 0; it < 4; ++it)                                             \
        glds16(bk_ + it * 4096, (char*)(SB) + it * 8192 + wid * 1024);         \
} while (0)

#define G1_COMPUTE(SA, SB) do {                                                \
    __builtin_amdgcn_s_setprio(1);                                             \
    _Pragma("unroll")                                                          \
    for (int ks = 0; ks < 2; ++ks) {                                           \
        bf16x8 af[4], bg[2], bu[2];                                            \
        _Pragma("unroll")                                                      \
        for (int m = 0; m < 4; ++m) {                                          \
            int row = wm * 64 + m * 16 + lrow;                                 \
            af[m] = *reinterpret_cast<const bf16x8*>(                          \
                &(SA)[(row << 6) + ((ks * 32 + lk8) ^ ((row & 7) << 3))]);     \
        }                                                                      \
        _Pragma("unroll")                                                      \
        for (int n = 0; n < 2; ++n) {                                          \
            int rg = wn * 32 + n * 16 + lrow;                                  \
            bg[n] = *reinterpret_cast<const bf16x8*>(                          \
                &(SB)[(rg << 6) + ((ks * 32 + lk8) ^ ((rg & 7) << 3))]);       \
            int ru = rg + 128;                                                 \
            bu[n] = *reinterpret_cast<const bf16x8*>(                          \
                &(SB)[(ru << 6) + ((ks * 32 + lk8) ^ ((ru & 7) << 3))]);       \
        }                                                                      \
        _Pragma("unroll")                                                      \
        for (int m = 0; m < 4; ++m)                                            \
            _Pragma("unroll")                                                  \
            for (int n = 0; n < 2; ++n) {                                      \
                accg[m][n] = __builtin_amdgcn_mfma_f32_16x16x32_bf16(          \
                    af[m], bg[n], accg[m][n], 0, 0, 0);                        \
                accu[m][n] = __builtin_amdgcn_mfma_f32_16x16x32_bf16(          \
                    af[m], bu[n], accu[m][n], 0, 0, 0);                        \
            }                                                                  \
    }                                                                          \
    __builtin_amdgcn_s_setprio(0);                                             \
} while (0)

    G1_STAGE(sA0, sB0, 0);
    G1_STAGE(sA1, sB1, 1);
    asm volatile("s_waitcnt vmcnt(6)" ::: "memory");
    __builtin_amdgcn_s_barrier();
    #pragma unroll 1
    for (int kt = 0; kt < 32; kt += 2) {
        G1_COMPUTE(sA0, sB0);
        __builtin_amdgcn_s_barrier();               // all waves done reading buf0
        if (kt < 30) {
            G1_STAGE(sA0, sB0, kt + 2);
            asm volatile("s_waitcnt vmcnt(6)" ::: "memory");   // tile kt+1 landed
        } else {
            asm volatile("s_waitcnt vmcnt(0)" ::: "memory");
        }
        __builtin_amdgcn_s_barrier();               // buf1 ready for everyone
        G1_COMPUTE(sA1, sB1);
        __builtin_amdgcn_s_barrier();
        if (kt <= 28) {
            G1_STAGE(sA1, sB1, kt + 3);
            asm volatile("s_waitcnt vmcnt(6)" ::: "memory");
        } else {
            asm volatile("s_waitcnt vmcnt(0)" ::: "memory");
        }
        __builtin_amdgcn_s_barrier();
    }

    // epilogue: SwiGLU -> actT swizzled [128][64] K-tiles
    const int mt = (poffs[e] + mbase) >> 7;
    #pragma unroll
    for (int m = 0; m < 4; ++m)
        #pragma unroll
        for (int n = 0; n < 2; ++n)
            #pragma unroll
            for (int j = 0; j < 4; ++j) {
                int row = wm * 64 + m * 16 + ((lane >> 4) << 2) + j;
                if (mbase + row < cnt) {
                    int c = wn * 32 + n * 16 + lrow;   // 0..127 within i-tile
                    int ktile = ibt * 2 + (c >> 6);
                    int cc = c & 63;
                    float g = accg[m][n][j], u = accu[m][n][j];
                    float a = (g / (1.f + __expf(-g))) * u;
                    actT[((size_t)(mt * 12 + ktile) * 128 + row) * 64 +
                         (((cc >> 3) ^ (row & 7)) << 3) + (cc & 7)] = f2bf(a);
                }
            }
}

// ---------------- GEMM2: partial = bf16(w * actT.down^T), counted-vmcnt dbuf ----------------
__global__ __launch_bounds__(256, 2) void gemm2_kernel(
    const unsigned short* __restrict__ actT, const unsigned short* __restrict__ wg2,
    const int* __restrict__ counts, const int* __restrict__ poffs,
    const int* __restrict__ ntotp, const int* __restrict__ tmap,
    const int* __restrict__ toks, const float* __restrict__ wts,
    unsigned short* __restrict__ partial) {
    const int b = blockIdx.x;                 // 2304 = 16*144
    const int w = (b & 7) * 288 + (b >> 3);   // XCD-grouped
    const int ht = w / 144;                   // h-tile 0..15
    const int gt = w % 144;
    if (gt >= ntotp[0]) return;
    const int ent = tmap[gt];
    const int e = ent & 255;
    const int mbase = (ent >> 8) << 7;
    const int cnt = counts[e];
    const int tid = threadIdx.x;
    const int lane = tid & 63;
    const int wid = tid >> 6;
    const int wm = wid >> 1, wn = wid & 1;

    __shared__ unsigned short sA0[128 * 64], sA1[128 * 64];
    __shared__ unsigned short sB0[128 * 64], sB1[128 * 64];
    __shared__ int s_tok[128];
    __shared__ float s_wt[128];

    if (tid < 128) {
        int r = mbase + tid;
        int rc = (r < cnt) ? r : (cnt - 1);
        s_tok[tid] = toks[e * CAP + rc];
        s_wt[tid] = wts[e * CAP + rc];
    }
    __syncthreads();   // drain vmcnt + publish s_tok/s_wt

    const int mt = (poffs[e] + mbase) >> 7;
    const unsigned short* abase = actT + (size_t)(mt * 12) * 8192 + (size_t)tid * 8;
    const unsigned short* bbase = wg2 + (size_t)((e * 16 + ht) * 12) * 8192 + (size_t)tid * 8;

    f32x4 acc[4][4];
    #pragma unroll
    for (int m = 0; m < 4; ++m)
        #pragma unroll
        for (int n = 0; n < 4; ++n) acc[m][n] = (f32x4){0.f, 0.f, 0.f, 0.f};

    const int lrow = lane & 15;
    const int lk8 = (lane >> 4) << 3;

#define G2_STAGE(SA, SB, kt) do {                                              \
    _Pragma("unroll")                                                          \
    for (int it = 0; it < 4; ++it)                                             \
        glds16(abase + (size_t)(kt) * 8192 + it * 2048,                        \
               (char*)(SA) + it * 4096 + wid * 1024);                          \
    _Pragma("unroll")                                                          \
    for (int it = 0; it < 4; ++it)                                             \
        glds16(bbase + (size_t)(kt) * 8192 + it * 2048,                        \
               (char*)(SB) + it * 4096 + wid * 1024);                          \
} while (0)

#define G2_COMPUTE(SA, SB) do {                                                \
    __builtin_amdgcn_s_setprio(1);                                             \
    _Pragma("unroll")                                                          \
    for (int ks = 0; ks < 2; ++ks) {                                           \
        bf16x8 af[4], bb[4];                                                   \
        _Pragma("unroll")                                                      \
        for (int m = 0; m < 4; ++m) {                                          \
            int row = wm * 64 + m * 16 + lrow;                                 \
            af[m] = *reinterpret_cast<const bf16x8*>(                          \
                &(SA)[(row << 6) + ((ks * 32 + lk8) ^ ((row & 7) << 3))]);     \
        }                                                                      \
        _Pragma("unroll")                                                      \
        for (int n = 0; n < 4; ++n) {                                          \
            int rb = wn * 64 + n * 16 + lrow;                                  \
            bb[n] = *reinterpret_cast<const bf16x8*>(                          \
                &(SB)[(rb << 6) + ((ks * 32 + lk8) ^ ((rb & 7) << 3))]);       \
        }                                                                      \
        _Pragma("unroll")                                                      \
        for (int m = 0; m < 4; ++m)                                            \
            _Pragma("unroll")                                                  \
            for (int n = 0; n < 4; ++n)                                        \
                acc[m][n] = __builtin_amdgcn_mfma_f32_16x16x32_bf16(           \
                    af[m], bb[n], acc[m][n], 0, 0, 0);                         \
    }                                                                          \
    __builtin_amdgcn_s_setprio(0);                                             \
} while (0)

    G2_STAGE(sA0, sB0, 0);
    G2_STAGE(sA1, sB1, 1);
    asm volatile("s_waitcnt vmcnt(8)" ::: "memory");
    __builtin_amdgcn_s_barrier();
    #pragma unroll 1
    for (int kt = 0; kt < 12; kt += 2) {
        G2_COMPUTE(sA0, sB0);
        __builtin_amdgcn_s_barrier();
        if (kt < 10) {
            G2_STAGE(sA0, sB0, kt + 2);
            asm volatile("s_waitcnt vmcnt(8)" ::: "memory");
        } else {
            asm volatile("s_waitcnt vmcnt(0)" ::: "memory");
        }
        __builtin_amdgcn_s_barrier();
        G2_COMPUTE(sA1, sB1);
        __builtin_amdgcn_s_barrier();
        if (kt <= 8) {
            G2_STAGE(sA1, sB1, kt + 3);
            asm volatile("s_waitcnt vmcnt(8)" ::: "memory");
        } else {
            asm volatile("s_waitcnt vmcnt(0)" ::: "memory");
        }
        __builtin_amdgcn_s_barrier();
    }

    // guarded epilogue: pad rows must NOT store (R4 lesson)
    #pragma unroll
    for (int m = 0; m < 4; ++m) {
        int row = wm * 64 + m * 16 + ((lane >> 4) << 2);
        #pragma unroll
        for (int j = 0; j < 4; ++j) {
            if (mbase + row + j < cnt) {
                int v = s_tok[row + j];
                size_t rbase = ((size_t)(v >> 15) * TT + (v & 0x1FFF)) * HH + ht * 128;
                float w = s_wt[row + j];
                #pragma unroll
                for (int n = 0; n < 4; ++n)
                    partial[rbase + wn * 64 + n * 16 + lrow] = f2bf(acc[m][n][j] * w);
            }
        }
    }
}

// ---------------- combine: out = partial[0] + partial[1] (bf16 -> fp32) ----------------
__global__ void combine_kernel(const unsigned short* __restrict__ partial, float* __restrict__ out) {
    size_t i = (size_t)blockIdx.x * blockDim.x + threadIdx.x;  // one 8-chunk per thread
    const ushort8 a = reinterpret_cast<const ushort8*>(partial)[i];
    const ushort8 b = reinterpret_cast<const ushort8*>(partial + (size_t)TT * HH)[i];
    f32x8 o;
    #pragma unroll
    for (int j = 0; j < 8; ++j) o[j] = bf2f(a[j]) + bf2f(b[j]);
    *reinterpret_cast<f32x8*>(&out[i * 8]) = o;
}

extern "C" void kernel_launch(void* const* d_in, const int* in_sizes, int n_in,
                              void* d_out, int out_size, void* d_ws, size_t ws_size,
                              hipStream_t stream) {
    const float* hs = (const float*)d_in[0];
    const int* tki = (const int*)d_in[1];
    const float* tkw = (const float*)d_in[2];
    const float* gup = (const float*)d_in[3];
    const float* dwn = (const float*)d_in[4];
    float* out = (float*)d_out;

    char* ws = (char*)d_ws;
    int* counts = (int*)(ws);                                     // [0,64)
    int* poffs = (int*)(ws + 128);                                // [128,196)
    int* ntot = (int*)(ws + 224);                                 // [224,228)
    int* tmap = (int*)(ws + 256);                                 // [256,896)
    int* toks = (int*)(ws + 1024);                                // 1 MB
    float* wts = (float*)(ws + 1024 + (size_t)CAP * NE * 4);      // 1 MB
    unsigned short* hsb = (unsigned short*)(ws + 2098176);        // 33.55 MB
    unsigned short* wg1 = (unsigned short*)(ws + 35652608);       // 100.66 MB
    unsigned short* wg2 = (unsigned short*)(ws + 136315904);      // 50.33 MB
    unsigned short* actT = (unsigned short*)(ws + 186647552);     // 28.31 MB
    // partial[2][TT][HH] bf16 = 67.1 MB overlays [hsb, wg1-head] — both dead
    // after gemm1 completes (stream-ordered before gemm2).
    unsigned short* partial = (unsigned short*)(ws + 2098176);

    hipMemsetAsync(counts, 0, 1024, stream);
    route_kernel<<<TT / 256, 256, 0, stream>>>(tki, tkw, counts, toks, wts);
    scan_kernel<<<1, 64, 0, stream>>>(counts, poffs, ntot, tmap);
    cast_all_kernel<<<53248, 256, 0, stream>>>(gup, dwn, hs, wg1, wg2, hsb);
    gemm1_kernel<<<864, 512, 0, stream>>>(hsb, wg1, counts, poffs, ntot, tmap, toks, actT);
    gemm2_kernel<<<2304, 256, 0, stream>>>(actT, wg2, counts, poffs, ntot, tmap, toks, wts, partial);
    combine_kernel<<<(TT * HH / 8) / 256, 256, 0, stream>>>(partial, out);
}

// Round 10
// 362.403 us; speedup vs baseline: 1.2019x; 1.2019x over previous
//
#include <hip/hip_runtime.h>

#define TT 8192
#define HH 2048
#define II 768
#define NE 16
#define TOPK 2
#define CAP 16384

typedef float f32x4 __attribute__((ext_vector_type(4)));
typedef float f32x8 __attribute__((ext_vector_type(8)));
typedef short bf16x8 __attribute__((ext_vector_type(8)));
typedef unsigned short ushort8 __attribute__((ext_vector_type(8)));

__device__ __forceinline__ unsigned short f2bf(float f) {
    unsigned u = __builtin_bit_cast(unsigned, f);
    u += 0x7fffu + ((u >> 16) & 1u);
    return (unsigned short)(u >> 16);
}

__device__ __forceinline__ float bf2f(unsigned short u) {
    return __builtin_bit_cast(float, (unsigned)u << 16);
}

__device__ __forceinline__ void glds16(const void* g, void* l) {
    __builtin_amdgcn_global_load_lds((const __attribute__((address_space(1))) void*)g,
                                     (__attribute__((address_space(3))) void*)l, 16, 0, 0);
}

// ---------------- merged: wg1 cast | wg2 cast | hs cast | routing ----------------
// blocks [0,24576): gate_up -> wg1 pre-swizzled 256-row tiles
// blocks [24576,36864): down  -> wg2 pre-swizzled 128-row tiles
// blocks [36864,53248): hidden_states fp32 -> bf16 linear
// block 53248: routing + scan + tmap (runs concurrently with the cast blocks;
// its outputs are only read by gemm1, which starts after this kernel completes)
__global__ void cast_route_kernel(const float* __restrict__ gup, const float* __restrict__ dwn,
                                  const float* __restrict__ hs,
                                  const int* __restrict__ tki, const float* __restrict__ tkw,
                                  unsigned short* __restrict__ wg1, unsigned short* __restrict__ wg2,
                                  unsigned short* __restrict__ hsb,
                                  int* __restrict__ counts, int* __restrict__ poffs,
                                  int* __restrict__ ntot, int* __restrict__ tmap,
                                  int* __restrict__ toks, float* __restrict__ wts) {
    const int bid = blockIdx.x;
    if (bid < 24576) {
        size_t gid = (size_t)bid * 256 + threadIdx.x;  // 6,291,456 chunks
        int sc = gid & 7;
        int r = (gid >> 3) & 255;
        int kt = (gid >> 11) & 31;
        int rest = (int)(gid >> 16);      // e*6 + it
        int it = rest % 6;
        int e = rest / 6;
        int chunk = sc ^ (r & 7);
        int grow = (r < 128) ? (it * 128 + r) : (II + it * 128 + (r - 128));
        const float4* s = reinterpret_cast<const float4*>(
            &gup[((size_t)e * (2 * II) + grow) * HH + kt * 64 + chunk * 8]);
        float4 v0 = s[0], v1 = s[1];
        ushort8 o;
        o[0] = f2bf(v0.x); o[1] = f2bf(v0.y); o[2] = f2bf(v0.z); o[3] = f2bf(v0.w);
        o[4] = f2bf(v1.x); o[5] = f2bf(v1.y); o[6] = f2bf(v1.z); o[7] = f2bf(v1.w);
        *reinterpret_cast<ushort8*>(&wg1[gid * 8]) = o;
    } else if (bid < 36864) {
        size_t gid = (size_t)(bid - 24576) * 256 + threadIdx.x;  // 3,145,728 chunks
        int sc = gid & 7;
        int r = (gid >> 3) & 127;
        int kt = (int)((gid >> 10) % 12);
        int rest = (int)(gid / (12 << 10));  // e*16 + ht
        int ht = rest & 15;
        int e = rest >> 4;
        int chunk = sc ^ (r & 7);
        int hrow = ht * 128 + r;
        const float4* s = reinterpret_cast<const float4*>(
            &dwn[((size_t)e * HH + hrow) * II + kt * 64 + chunk * 8]);
        float4 v0 = s[0], v1 = s[1];
        ushort8 o;
        o[0] = f2bf(v0.x); o[1] = f2bf(v0.y); o[2] = f2bf(v0.z); o[3] = f2bf(v0.w);
        o[4] = f2bf(v1.x); o[5] = f2bf(v1.y); o[6] = f2bf(v1.z); o[7] = f2bf(v1.w);
        *reinterpret_cast<ushort8*>(&wg2[gid * 8]) = o;
    } else if (bid < 53248) {
        int i = (bid - 36864) * 256 + threadIdx.x;  // float4 chunks of hs
        const float4 v = reinterpret_cast<const float4*>(hs)[i];
        ushort4 o;
        o.x = f2bf(v.x); o.y = f2bf(v.y); o.z = f2bf(v.z); o.w = f2bf(v.w);
        reinterpret_cast<ushort4*>(hsb)[i] = o;
    } else {
        // routing block: LDS-counted bucket append, then serial scan + tile map
        __shared__ int lcnt[NE];
        const int tid = threadIdx.x;
        if (tid < NE) lcnt[tid] = 0;
        __syncthreads();
        for (int t = tid; t < TT; t += 256) {
            #pragma unroll
            for (int k = 0; k < TOPK; ++k) {
                int e = tki[t * TOPK + k];
                int p = atomicAdd(&lcnt[e], 1);
                toks[e * CAP + p] = t | (k << 15);
                wts[e * CAP + p] = tkw[t * TOPK + k];
            }
        }
        __syncthreads();
        if (tid == 0) {
            int s = 0, nt = 0;
            for (int e = 0; e < NE; ++e) {
                counts[e] = lcnt[e];
                poffs[e] = s;
                int ct = (lcnt[e] + 127) >> 7;
                for (int m = 0; m < ct; ++m) tmap[nt++] = e | (m << 8);
                s += ct << 7;
            }
            poffs[NE] = s;
            ntot[0] = nt;
        }
    }
}

// ---------------- GEMM1: actT[slot, i] = silu(hs.Wg) * (hs.Wu), 128x128 tile ----------------
// Single-buffer structure, 3 blocks/CU. R7+R9 lessons: at this tile size any
// explicit dbuf (96KB -> 1 block/CU) loses to implicit inter-block overlap.
__global__ __launch_bounds__(256, 2) void gemm1_kernel(
    const unsigned short* __restrict__ hsb, const unsigned short* __restrict__ wg1,
    const int* __restrict__ counts, const int* __restrict__ poffs,
    const int* __restrict__ ntotp, const int* __restrict__ tmap,
    const int* __restrict__ toks, unsigned short* __restrict__ actT) {
    const int b = blockIdx.x;                 // 864 = 6*144
    const int w = (b & 7) * 108 + (b >> 3);   // XCD-grouped
    const int ibt = w / 144;                  // i-tile 0..5
    const int gt = w % 144;
    if (gt >= ntotp[0]) return;
    const int ent = tmap[gt];
    const int e = ent & 255;
    const int mbase = (ent >> 8) << 7;
    const int cnt = counts[e];
    const int tid = threadIdx.x;
    const int lane = tid & 63;
    const int wid = tid >> 6;
    const int wm = wid >> 1, wn = wid & 1;

    __shared__ unsigned short sA[128 * 64];
    __shared__ unsigned short sB[256 * 64];
    __shared__ int s_tok[128];

    if (tid < 128) {
        int r = mbase + tid;
        s_tok[tid] = toks[e * CAP + ((r < cnt) ? r : (cnt - 1))] & 0x1FFF;
    }
    __syncthreads();

    size_t abase[4];
    #pragma unroll
    for (int it = 0; it < 4; ++it) {
        int idx = it * 256 + tid;
        int r = idx >> 3, sc = idx & 7;
        abase[it] = (size_t)s_tok[r] * HH + ((sc ^ (r & 7)) << 3);
    }
    const unsigned short* bbase = wg1 + ((size_t)(e * 6 + ibt) << 19) + (size_t)tid * 8;

    f32x4 accg[4][4], accu[4][4];
    #pragma unroll
    for (int m = 0; m < 4; ++m)
        #pragma unroll
        for (int n = 0; n < 4; ++n) {
            accg[m][n] = (f32x4){0.f, 0.f, 0.f, 0.f};
            accu[m][n] = (f32x4){0.f, 0.f, 0.f, 0.f};
        }

    const int lrow = lane & 15;
    const int lk8 = (lane >> 4) << 3;

    for (int k0 = 0; k0 < HH; k0 += 64) {
        #pragma unroll
        for (int it = 0; it < 4; ++it)
            glds16(hsb + abase[it] + k0, (char*)sA + it * 4096 + wid * 1024);
        const unsigned short* bk = bbase + ((size_t)(k0 >> 6) * 16384);
        #pragma unroll
        for (int it = 0; it < 8; ++it)
            glds16(bk + it * 2048, (char*)sB + it * 4096 + wid * 1024);
        __syncthreads();
        #pragma unroll
        for (int ks = 0; ks < 2; ++ks) {
            bf16x8 af[4], bg[4], bu[4];
            #pragma unroll
            for (int m = 0; m < 4; ++m) {
                int row = wm * 64 + m * 16 + lrow;
                af[m] = *reinterpret_cast<const bf16x8*>(
                    &sA[(row << 6) + ((ks * 32 + lk8) ^ ((row & 7) << 3))]);
            }
            #pragma unroll
            for (int n = 0; n < 4; ++n) {
                int rg = wn * 64 + n * 16 + lrow;
                bg[n] = *reinterpret_cast<const bf16x8*>(
                    &sB[(rg << 6) + ((ks * 32 + lk8) ^ ((rg & 7) << 3))]);
                int ru = rg + 128;
                bu[n] = *reinterpret_cast<const bf16x8*>(
                    &sB[(ru << 6) + ((ks * 32 + lk8) ^ ((ru & 7) << 3))]);
            }
            #pragma unroll
            for (int m = 0; m < 4; ++m)
                #pragma unroll
                for (int n = 0; n < 4; ++n) {
                    accg[m][n] = __builtin_amdgcn_mfma_f32_16x16x32_bf16(af[m], bg[n], accg[m][n], 0, 0, 0);
                    accu[m][n] = __builtin_amdgcn_mfma_f32_16x16x32_bf16(af[m], bu[n], accu[m][n], 0, 0, 0);
                }
        }
        __syncthreads();
    }

    // epilogue: SwiGLU -> actT swizzled [128][64] K-tiles
    const int mt = (poffs[e] + mbase) >> 7;
    #pragma unroll
    for (int m = 0; m < 4; ++m)
        #pragma unroll
        for (int n = 0; n < 4; ++n)
            #pragma unroll
            for (int j = 0; j < 4; ++j) {
                int row = wm * 64 + m * 16 + ((lane >> 4) << 2) + j;
                if (mbase + row < cnt) {
                    int c = wn * 64 + n * 16 + lrow;   // 0..127 within i-tile
                    int ktile = ibt * 2 + (c >> 6);
                    int cc = c & 63;
                    float g = accg[m][n][j], u = accu[m][n][j];
                    float a = (g / (1.f + __expf(-g))) * u;
                    actT[((size_t)(mt * 12 + ktile) * 128 + row) * 64 +
                         (((cc >> 3) ^ (row & 7)) << 3) + (cc & 7)] = f2bf(a);
                }
            }
}

// ---------------- GEMM2: partial[k][tok][h] = bf16( w * (actT . down^T) ) ----------------
__global__ __launch_bounds__(256) void gemm2_kernel(
    const unsigned short* __restrict__ actT, const unsigned short* __restrict__ wg2,
    const int* __restrict__ counts, const int* __restrict__ poffs,
    const int* __restrict__ ntotp, const int* __restrict__ tmap,
    const int* __restrict__ toks, const float* __restrict__ wts,
    unsigned short* __restrict__ partial) {
    const int b = blockIdx.x;                 // 2304 = 16*144
    const int w = (b & 7) * 288 + (b >> 3);   // XCD-grouped
    const int ht = w / 144;                   // h-tile 0..15
    const int gt = w % 144;
    if (gt >= ntotp[0]) return;
    const int ent = tmap[gt];
    const int e = ent & 255;
    const int mbase = (ent >> 8) << 7;
    const int cnt = counts[e];
    const int tid = threadIdx.x;
    const int lane = tid & 63;
    const int wid = tid >> 6;
    const int wm = wid >> 1, wn = wid & 1;

    __shared__ unsigned short sA[128 * 64];
    __shared__ unsigned short sB[128 * 64];
    __shared__ int s_tok[128];
    __shared__ float s_wt[128];

    if (tid < 128) {
        int r = mbase + tid;
        int rc = (r < cnt) ? r : (cnt - 1);
        s_tok[tid] = toks[e * CAP + rc];
        s_wt[tid] = wts[e * CAP + rc];
    }

    const int mt = (poffs[e] + mbase) >> 7;
    const unsigned short* abase = actT + (size_t)(mt * 12) * 8192 + (size_t)tid * 8;
    const unsigned short* bbase = wg2 + (size_t)((e * 16 + ht) * 12) * 8192 + (size_t)tid * 8;

    f32x4 acc[4][4];
    #pragma unroll
    for (int m = 0; m < 4; ++m)
        #pragma unroll
        for (int n = 0; n < 4; ++n) acc[m][n] = (f32x4){0.f, 0.f, 0.f, 0.f};

    const int lrow = lane & 15;
    const int lk8 = (lane >> 4) << 3;

    for (int kt = 0; kt < 12; ++kt) {
        #pragma unroll
        for (int it = 0; it < 4; ++it)
            glds16(abase + (size_t)kt * 8192 + it * 2048, (char*)sA + it * 4096 + wid * 1024);
        #pragma unroll
        for (int it = 0; it < 4; ++it)
            glds16(bbase + (size_t)kt * 8192 + it * 2048, (char*)sB + it * 4096 + wid * 1024);
        __syncthreads();
        #pragma unroll
        for (int ks = 0; ks < 2; ++ks) {
            bf16x8 af[4], bb[4];
            #pragma unroll
            for (int m = 0; m < 4; ++m) {
                int row = wm * 64 + m * 16 + lrow;
                af[m] = *reinterpret_cast<const bf16x8*>(
                    &sA[(row << 6) + ((ks * 32 + lk8) ^ ((row & 7) << 3))]);
            }
            #pragma unroll
            for (int n = 0; n < 4; ++n) {
                int rb = wn * 64 + n * 16 + lrow;
                bb[n] = *reinterpret_cast<const bf16x8*>(
                    &sB[(rb << 6) + ((ks * 32 + lk8) ^ ((rb & 7) << 3))]);
            }
            #pragma unroll
            for (int m = 0; m < 4; ++m)
                #pragma unroll
                for (int n = 0; n < 4; ++n)
                    acc[m][n] = __builtin_amdgcn_mfma_f32_16x16x32_bf16(af[m], bb[n], acc[m][n], 0, 0, 0);
        }
        __syncthreads();
    }

    // guarded epilogue: pad rows must NOT store (R4 lesson)
    #pragma unroll
    for (int m = 0; m < 4; ++m) {
        int row = wm * 64 + m * 16 + ((lane >> 4) << 2);
        #pragma unroll
        for (int j = 0; j < 4; ++j) {
            if (mbase + row + j < cnt) {
                int v = s_tok[row + j];
                size_t rbase = ((size_t)(v >> 15) * TT + (v & 0x1FFF)) * HH + ht * 128;
                float w = s_wt[row + j];
                #pragma unroll
                for (int n = 0; n < 4; ++n)
                    partial[rbase + wn * 64 + n * 16 + lrow] = f2bf(acc[m][n][j] * w);
            }
        }
    }
}

// ---------------- combine: out = partial[0] + partial[1] (bf16 -> fp32) ----------------
__global__ void combine_kernel(const unsigned short* __restrict__ partial, float* __restrict__ out) {
    size_t i = (size_t)blockIdx.x * blockDim.x + threadIdx.x;  // one 8-chunk per thread
    const ushort8 a = reinterpret_cast<const ushort8*>(partial)[i];
    const ushort8 b = reinterpret_cast<const ushort8*>(partial + (size_t)TT * HH)[i];
    f32x8 o;
    #pragma unroll
    for (int j = 0; j < 8; ++j) o[j] = bf2f(a[j]) + bf2f(b[j]);
    *reinterpret_cast<f32x8*>(&out[i * 8]) = o;
}

extern "C" void kernel_launch(void* const* d_in, const int* in_sizes, int n_in,
                              void* d_out, int out_size, void* d_ws, size_t ws_size,
                              hipStream_t stream) {
    const float* hs = (const float*)d_in[0];
    const int* tki = (const int*)d_in[1];
    const float* tkw = (const float*)d_in[2];
    const float* gup = (const float*)d_in[3];
    const float* dwn = (const float*)d_in[4];
    float* out = (float*)d_out;

    char* ws = (char*)d_ws;
    int* counts = (int*)(ws);                                     // [0,64)
    int* poffs = (int*)(ws + 128);                                // [128,196)
    int* ntot = (int*)(ws + 224);                                 // [224,228)
    int* tmap = (int*)(ws + 256);                                 // [256,896)
    int* toks = (int*)(ws + 1024);                                // 1 MB
    float* wts = (float*)(ws + 1024 + (size_t)CAP * NE * 4);      // 1 MB
    unsigned short* hsb = (unsigned short*)(ws + 2098176);        // 33.55 MB
    unsigned short* wg1 = (unsigned short*)(ws + 35652608);       // 100.66 MB
    unsigned short* wg2 = (unsigned short*)(ws + 136315904);      // 50.33 MB
    unsigned short* actT = (unsigned short*)(ws + 186647552);     // 28.31 MB
    // partial[2][TT][HH] bf16 = 67.1 MB overlays [hsb, wg1-head] — both dead
    // after gemm1 completes (stream-ordered before gemm2).
    unsigned short* partial = (unsigned short*)(ws + 2098176);

    cast_route_kernel<<<53249, 256, 0, stream>>>(gup, dwn, hs, tki, tkw,
                                                 wg1, wg2, hsb,
                                                 counts, poffs, ntot, tmap, toks, wts);
    gemm1_kernel<<<864, 256, 0, stream>>>(hsb, wg1, counts, poffs, ntot, tmap, toks, actT);
    gemm2_kernel<<<2304, 256, 0, stream>>>(actT, wg2, counts, poffs, ntot, tmap, toks, wts, partial);
    combine_kernel<<<(TT * HH / 8) / 256, 256, 0, stream>>>(partial, out);
}

// Round 11
// 357.667 us; speedup vs baseline: 1.2178x; 1.0132x over previous
//
#include <hip/hip_runtime.h>

#define TT 8192
#define HH 2048
#define II 768
#define NE 16
#define TOPK 2
#define CAP 16384

typedef float f32x4 __attribute__((ext_vector_type(4)));
typedef float f32x8 __attribute__((ext_vector_type(8)));
typedef short bf16x8 __attribute__((ext_vector_type(8)));
typedef unsigned short ushort8 __attribute__((ext_vector_type(8)));
typedef unsigned short ushort16 __attribute__((ext_vector_type(16)));

__device__ __forceinline__ unsigned short f2bf(float f) {
    unsigned u = __builtin_bit_cast(unsigned, f);
    u += 0x7fffu + ((u >> 16) & 1u);
    return (unsigned short)(u >> 16);
}

__device__ __forceinline__ float bf2f(unsigned short u) {
    return __builtin_bit_cast(float, (unsigned)u << 16);
}

__device__ __forceinline__ void glds16(const void* g, void* l) {
    __builtin_amdgcn_global_load_lds((const __attribute__((address_space(1))) void*)g,
                                     (__attribute__((address_space(3))) void*)l, 16, 0, 0);
}

// ---------------- merged: routing | wg1 cast | wg2 cast | hs cast ----------------
// bid 0:               routing + scan + tmap (FIRST so its scattered-store tail
//                      hides under the cast blocks; R10 had it last = serial tail)
// bids [1, 12289):     gate_up -> wg1 pre-swizzled tiles   (2 chunks/thread)
// bids [12289, 18433): down    -> wg2 pre-swizzled tiles   (2 chunks/thread)
// bids [18433, 22529): hidden_states fp32 -> bf16 linear   (16 floats/thread)
__global__ void cast_route_kernel(const float* __restrict__ gup, const float* __restrict__ dwn,
                                  const float* __restrict__ hs,
                                  const int* __restrict__ tki, const float* __restrict__ tkw,
                                  unsigned short* __restrict__ wg1, unsigned short* __restrict__ wg2,
                                  unsigned short* __restrict__ hsb,
                                  int* __restrict__ counts, int* __restrict__ poffs,
                                  int* __restrict__ ntot, int* __restrict__ tmap,
                                  int* __restrict__ toks, float* __restrict__ wts) {
    const int bid = blockIdx.x;
    if (bid == 0) {
        // routing block: LDS-counted bucket append, then serial scan + tile map
        __shared__ int lcnt[NE];
        const int tid = threadIdx.x;
        if (tid < NE) lcnt[tid] = 0;
        __syncthreads();
        for (int t = tid; t < TT; t += 256) {
            #pragma unroll
            for (int k = 0; k < TOPK; ++k) {
                int e = tki[t * TOPK + k];
                int p = atomicAdd(&lcnt[e], 1);
                toks[e * CAP + p] = t | (k << 15);
                wts[e * CAP + p] = tkw[t * TOPK + k];
            }
        }
        __syncthreads();
        if (tid == 0) {
            int s = 0, nt = 0;
            for (int e = 0; e < NE; ++e) {
                counts[e] = lcnt[e];
                poffs[e] = s;
                int ct = (lcnt[e] + 127) >> 7;
                for (int m = 0; m < ct; ++m) tmap[nt++] = e | (m << 8);
                s += ct << 7;
            }
            poffs[NE] = s;
            ntot[0] = nt;
        }
    } else if (bid < 12289) {
        size_t gid0 = (size_t)(bid - 1) * 512 + threadIdx.x * 2;   // even chunk index
        int sc = gid0 & 7;                 // even
        int r = (gid0 >> 3) & 255;
        int kt = (gid0 >> 11) & 31;
        int rest = (int)(gid0 >> 16);      // e*6 + it
        int it = rest % 6;
        int e = rest / 6;
        int grow = (r < 128) ? (it * 128 + r) : (II + it * 128 + (r - 128));
        const float* rp = &gup[((size_t)e * (2 * II) + grow) * HH + kt * 64];
        int c0 = sc ^ (r & 7), c1 = c0 ^ 1;   // chunks for gid0, gid0+1
        const float4 a0 = *reinterpret_cast<const float4*>(rp + c0 * 8);
        const float4 a1 = *reinterpret_cast<const float4*>(rp + c0 * 8 + 4);
        const float4 b0 = *reinterpret_cast<const float4*>(rp + c1 * 8);
        const float4 b1 = *reinterpret_cast<const float4*>(rp + c1 * 8 + 4);
        ushort16 o;
        o[0] = f2bf(a0.x); o[1] = f2bf(a0.y); o[2]  = f2bf(a0.z); o[3]  = f2bf(a0.w);
        o[4] = f2bf(a1.x); o[5] = f2bf(a1.y); o[6]  = f2bf(a1.z); o[7]  = f2bf(a1.w);
        o[8] = f2bf(b0.x); o[9] = f2bf(b0.y); o[10] = f2bf(b0.z); o[11] = f2bf(b0.w);
        o[12] = f2bf(b1.x); o[13] = f2bf(b1.y); o[14] = f2bf(b1.z); o[15] = f2bf(b1.w);
        *reinterpret_cast<ushort16*>(&wg1[gid0 * 8]) = o;
    } else if (bid < 18433) {
        size_t gid0 = (size_t)(bid - 12289) * 512 + threadIdx.x * 2;
        int sc = gid0 & 7;                 // even
        int r = (gid0 >> 3) & 127;
        int kt = (int)((gid0 >> 10) % 12);
        int rest = (int)(gid0 / (12 << 10));  // e*16 + ht
        int ht = rest & 15;
        int e = rest >> 4;
        int hrow = ht * 128 + r;
        const float* rp = &dwn[((size_t)e * HH + hrow) * II + kt * 64];
        int c0 = sc ^ (r & 7), c1 = c0 ^ 1;
        const float4 a0 = *reinterpret_cast<const float4*>(rp + c0 * 8);
        const float4 a1 = *reinterpret_cast<const float4*>(rp + c0 * 8 + 4);
        const float4 b0 = *reinterpret_cast<const float4*>(rp + c1 * 8);
        const float4 b1 = *reinterpret_cast<const float4*>(rp + c1 * 8 + 4);
        ushort16 o;
        o[0] = f2bf(a0.x); o[1] = f2bf(a0.y); o[2]  = f2bf(a0.z); o[3]  = f2bf(a0.w);
        o[4] = f2bf(a1.x); o[5] = f2bf(a1.y); o[6]  = f2bf(a1.z); o[7]  = f2bf(a1.w);
        o[8] = f2bf(b0.x); o[9] = f2bf(b0.y); o[10] = f2bf(b0.z); o[11] = f2bf(b0.w);
        o[12] = f2bf(b1.x); o[13] = f2bf(b1.y); o[14] = f2bf(b1.z); o[15] = f2bf(b1.w);
        *reinterpret_cast<ushort16*>(&wg2[gid0 * 8]) = o;
    } else {
        size_t i0 = ((size_t)(bid - 18433) * 256 + threadIdx.x) * 4;  // float4 chunks
        const float4* src = reinterpret_cast<const float4*>(hs);
        const float4 v0 = src[i0], v1 = src[i0 + 1], v2 = src[i0 + 2], v3 = src[i0 + 3];
        ushort16 o;
        o[0] = f2bf(v0.x); o[1] = f2bf(v0.y); o[2]  = f2bf(v0.z); o[3]  = f2bf(v0.w);
        o[4] = f2bf(v1.x); o[5] = f2bf(v1.y); o[6]  = f2bf(v1.z); o[7]  = f2bf(v1.w);
        o[8] = f2bf(v2.x); o[9] = f2bf(v2.y); o[10] = f2bf(v2.z); o[11] = f2bf(v2.w);
        o[12] = f2bf(v3.x); o[13] = f2bf(v3.y); o[14] = f2bf(v3.z); o[15] = f2bf(v3.w);
        *reinterpret_cast<ushort16*>(&hsb[i0 * 4]) = o;
    }
}

// ---------------- GEMM1: actT[slot, i] = silu(hs.Wg) * (hs.Wu), 128x128 tile ----------------
// Single-buffer structure, 3 blocks/CU. R7+R9 lessons: at this tile size any
// explicit dbuf (96KB -> 1 block/CU) loses to implicit inter-block overlap.
__global__ __launch_bounds__(256, 2) void gemm1_kernel(
    const unsigned short* __restrict__ hsb, const unsigned short* __restrict__ wg1,
    const int* __restrict__ counts, const int* __restrict__ poffs,
    const int* __restrict__ ntotp, const int* __restrict__ tmap,
    const int* __restrict__ toks, unsigned short* __restrict__ actT) {
    const int b = blockIdx.x;                 // 864 = 6*144
    const int w = (b & 7) * 108 + (b >> 3);   // XCD-grouped
    const int ibt = w / 144;                  // i-tile 0..5
    const int gt = w % 144;
    if (gt >= ntotp[0]) return;
    const int ent = tmap[gt];
    const int e = ent & 255;
    const int mbase = (ent >> 8) << 7;
    const int cnt = counts[e];
    const int tid = threadIdx.x;
    const int lane = tid & 63;
    const int wid = tid >> 6;
    const int wm = wid >> 1, wn = wid & 1;

    __shared__ unsigned short sA[128 * 64];
    __shared__ unsigned short sB[256 * 64];
    __shared__ int s_tok[128];

    if (tid < 128) {
        int r = mbase + tid;
        s_tok[tid] = toks[e * CAP + ((r < cnt) ? r : (cnt - 1))] & 0x1FFF;
    }
    __syncthreads();

    size_t abase[4];
    #pragma unroll
    for (int it = 0; it < 4; ++it) {
        int idx = it * 256 + tid;
        int r = idx >> 3, sc = idx & 7;
        abase[it] = (size_t)s_tok[r] * HH + ((sc ^ (r & 7)) << 3);
    }
    const unsigned short* bbase = wg1 + ((size_t)(e * 6 + ibt) << 19) + (size_t)tid * 8;

    f32x4 accg[4][4], accu[4][4];
    #pragma unroll
    for (int m = 0; m < 4; ++m)
        #pragma unroll
        for (int n = 0; n < 4; ++n) {
            accg[m][n] = (f32x4){0.f, 0.f, 0.f, 0.f};
            accu[m][n] = (f32x4){0.f, 0.f, 0.f, 0.f};
        }

    const int lrow = lane & 15;
    const int lk8 = (lane >> 4) << 3;

    for (int k0 = 0; k0 < HH; k0 += 64) {
        #pragma unroll
        for (int it = 0; it < 4; ++it)
            glds16(hsb + abase[it] + k0, (char*)sA + it * 4096 + wid * 1024);
        const unsigned short* bk = bbase + ((size_t)(k0 >> 6) * 16384);
        #pragma unroll
        for (int it = 0; it < 8; ++it)
            glds16(bk + it * 2048, (char*)sB + it * 4096 + wid * 1024);
        __syncthreads();
        #pragma unroll
        for (int ks = 0; ks < 2; ++ks) {
            bf16x8 af[4], bg[4], bu[4];
            #pragma unroll
            for (int m = 0; m < 4; ++m) {
                int row = wm * 64 + m * 16 + lrow;
                af[m] = *reinterpret_cast<const bf16x8*>(
                    &sA[(row << 6) + ((ks * 32 + lk8) ^ ((row & 7) << 3))]);
            }
            #pragma unroll
            for (int n = 0; n < 4; ++n) {
                int rg = wn * 64 + n * 16 + lrow;
                bg[n] = *reinterpret_cast<const bf16x8*>(
                    &sB[(rg << 6) + ((ks * 32 + lk8) ^ ((rg & 7) << 3))]);
                int ru = rg + 128;
                bu[n] = *reinterpret_cast<const bf16x8*>(
                    &sB[(ru << 6) + ((ks * 32 + lk8) ^ ((ru & 7) << 3))]);
            }
            #pragma unroll
            for (int m = 0; m < 4; ++m)
                #pragma unroll
                for (int n = 0; n < 4; ++n) {
                    accg[m][n] = __builtin_amdgcn_mfma_f32_16x16x32_bf16(af[m], bg[n], accg[m][n], 0, 0, 0);
                    accu[m][n] = __builtin_amdgcn_mfma_f32_16x16x32_bf16(af[m], bu[n], accu[m][n], 0, 0, 0);
                }
        }
        __syncthreads();
    }

    // epilogue: SwiGLU -> actT swizzled [128][64] K-tiles
    const int mt = (poffs[e] + mbase) >> 7;
    #pragma unroll
    for (int m = 0; m < 4; ++m)
        #pragma unroll
        for (int n = 0; n < 4; ++n)
            #pragma unroll
            for (int j = 0; j < 4; ++j) {
                int row = wm * 64 + m * 16 + ((lane >> 4) << 2) + j;
                if (mbase + row < cnt) {
                    int c = wn * 64 + n * 16 + lrow;   // 0..127 within i-tile
                    int ktile = ibt * 2 + (c >> 6);
                    int cc = c & 63;
                    float g = accg[m][n][j], u = accu[m][n][j];
                    float a = (g / (1.f + __expf(-g))) * u;
                    actT[((size_t)(mt * 12 + ktile) * 128 + row) * 64 +
                         (((cc >> 3) ^ (row & 7)) << 3) + (cc & 7)] = f2bf(a);
                }
            }
}

// ---------------- GEMM2: partial[k][tok][h] = bf16( w * (actT . down^T) ) ----------------
__global__ __launch_bounds__(256) void gemm2_kernel(
    const unsigned short* __restrict__ actT, const unsigned short* __restrict__ wg2,
    const int* __restrict__ counts, const int* __restrict__ poffs,
    const int* __restrict__ ntotp, const int* __restrict__ tmap,
    const int* __restrict__ toks, const float* __restrict__ wts,
    unsigned short* __restrict__ partial) {
    const int b = blockIdx.x;                 // 2304 = 16*144
    const int w = (b & 7) * 288 + (b >> 3);   // XCD-grouped
    const int ht = w / 144;                   // h-tile 0..15
    const int gt = w % 144;
    if (gt >= ntotp[0]) return;
    const int ent = tmap[gt];
    const int e = ent & 255;
    const int mbase = (ent >> 8) << 7;
    const int cnt = counts[e];
    const int tid = threadIdx.x;
    const int lane = tid & 63;
    const int wid = tid >> 6;
    const int wm = wid >> 1, wn = wid & 1;

    __shared__ unsigned short sA[128 * 64];
    __shared__ unsigned short sB[128 * 64];
    __shared__ int s_tok[128];
    __shared__ float s_wt[128];

    if (tid < 128) {
        int r = mbase + tid;
        int rc = (r < cnt) ? r : (cnt - 1);
        s_tok[tid] = toks[e * CAP + rc];
        s_wt[tid] = wts[e * CAP + rc];
    }

    const int mt = (poffs[e] + mbase) >> 7;
    const unsigned short* abase = actT + (size_t)(mt * 12) * 8192 + (size_t)tid * 8;
    const unsigned short* bbase = wg2 + (size_t)((e * 16 + ht) * 12) * 8192 + (size_t)tid * 8;

    f32x4 acc[4][4];
    #pragma unroll
    for (int m = 0; m < 4; ++m)
        #pragma unroll
        for (int n = 0; n < 4; ++n) acc[m][n] = (f32x4){0.f, 0.f, 0.f, 0.f};

    const int lrow = lane & 15;
    const int lk8 = (lane >> 4) << 3;

    for (int kt = 0; kt < 12; ++kt) {
        #pragma unroll
        for (int it = 0; it < 4; ++it)
            glds16(abase + (size_t)kt * 8192 + it * 2048, (char*)sA + it * 4096 + wid * 1024);
        #pragma unroll
        for (int it = 0; it < 4; ++it)
            glds16(bbase + (size_t)kt * 8192 + it * 2048, (char*)sB + it * 4096 + wid * 1024);
        __syncthreads();
        #pragma unroll
        for (int ks = 0; ks < 2; ++ks) {
            bf16x8 af[4], bb[4];
            #pragma unroll
            for (int m = 0; m < 4; ++m) {
                int row = wm * 64 + m * 16 + lrow;
                af[m] = *reinterpret_cast<const bf16x8*>(
                    &sA[(row << 6) + ((ks * 32 + lk8) ^ ((row & 7) << 3))]);
            }
            #pragma unroll
            for (int n = 0; n < 4; ++n) {
                int rb = wn * 64 + n * 16 + lrow;
                bb[n] = *reinterpret_cast<const bf16x8*>(
                    &sB[(rb << 6) + ((ks * 32 + lk8) ^ ((rb & 7) << 3))]);
            }
            #pragma unroll
            for (int m = 0; m < 4; ++m)
                #pragma unroll
                for (int n = 0; n < 4; ++n)
                    acc[m][n] = __builtin_amdgcn_mfma_f32_16x16x32_bf16(af[m], bb[n], acc[m][n], 0, 0, 0);
        }
        __syncthreads();
    }

    // guarded epilogue: pad rows must NOT store (R4 lesson)
    #pragma unroll
    for (int m = 0; m < 4; ++m) {
        int row = wm * 64 + m * 16 + ((lane >> 4) << 2);
        #pragma unroll
        for (int j = 0; j < 4; ++j) {
            if (mbase + row + j < cnt) {
                int v = s_tok[row + j];
                size_t rbase = ((size_t)(v >> 15) * TT + (v & 0x1FFF)) * HH + ht * 128;
                float w = s_wt[row + j];
                #pragma unroll
                for (int n = 0; n < 4; ++n)
                    partial[rbase + wn * 64 + n * 16 + lrow] = f2bf(acc[m][n][j] * w);
            }
        }
    }
}

// ---------------- combine: out = partial[0] + partial[1] (bf16 -> fp32) ----------------
__global__ void combine_kernel(const unsigned short* __restrict__ partial, float* __restrict__ out) {
    size_t i = ((size_t)blockIdx.x * blockDim.x + threadIdx.x) * 2;  // two 8-chunks per thread
    const ushort8* pa = reinterpret_cast<const ushort8*>(partial);
    const ushort8* pb = reinterpret_cast<const ushort8*>(partial + (size_t)TT * HH);
    const ushort8 a0 = pa[i], a1 = pa[i + 1];
    const ushort8 b0 = pb[i], b1 = pb[i + 1];
    f32x8 o0, o1;
    #pragma unroll
    for (int j = 0; j < 8; ++j) { o0[j] = bf2f(a0[j]) + bf2f(b0[j]); o1[j] = bf2f(a1[j]) + bf2f(b1[j]); }
    *reinterpret_cast<f32x8*>(&out[i * 8]) = o0;
    *reinterpret_cast<f32x8*>(&out[i * 8 + 8]) = o1;
}

extern "C" void kernel_launch(void* const* d_in, const int* in_sizes, int n_in,
                              void* d_out, int out_size, void* d_ws, size_t ws_size,
                              hipStream_t stream) {
    const float* hs = (const float*)d_in[0];
    const int* tki = (const int*)d_in[1];
    const float* tkw = (const float*)d_in[2];
    const float* gup = (const float*)d_in[3];
    const float* dwn = (const float*)d_in[4];
    float* out = (float*)d_out;

    char* ws = (char*)d_ws;
    int* counts = (int*)(ws);                                     // [0,64)
    int* poffs = (int*)(ws + 128);                                // [128,196)
    int* ntot = (int*)(ws + 224);                                 // [224,228)
    int* tmap = (int*)(ws + 256);                                 // [256,896)
    int* toks = (int*)(ws + 1024);                                // 1 MB
    float* wts = (float*)(ws + 1024 + (size_t)CAP * NE * 4);      // 1 MB
    unsigned short* hsb = (unsigned short*)(ws + 2098176);        // 33.55 MB
    unsigned short* wg1 = (unsigned short*)(ws + 35652608);       // 100.66 MB
    unsigned short* wg2 = (unsigned short*)(ws + 136315904);      // 50.33 MB
    unsigned short* actT = (unsigned short*)(ws + 186647552);     // 28.31 MB
    // partial[2][TT][HH] bf16 = 67.1 MB overlays [hsb, wg1-head] — both dead
    // after gemm1 completes (stream-ordered before gemm2).
    unsigned short* partial = (unsigned short*)(ws + 2098176);

    cast_route_kernel<<<22529, 256, 0, stream>>>(gup, dwn, hs, tki, tkw,
                                                 wg1, wg2, hsb,
                                                 counts, poffs, ntot, tmap, toks, wts);
    gemm1_kernel<<<864, 256, 0, stream>>>(hsb, wg1, counts, poffs, ntot, tmap, toks, actT);
    gemm2_kernel<<<2304, 256, 0, stream>>>(actT, wg2, counts, poffs, ntot, tmap, toks, wts, partial);
    combine_kernel<<<(TT * HH / 16) / 256, 256, 0, stream>>>(partial, out);
}

// Round 12
// 343.280 us; speedup vs baseline: 1.2688x; 1.0419x over previous
//
#include <hip/hip_runtime.h>

#define TT 8192
#define HH 2048
#define II 768
#define NE 16
#define TOPK 2
#define CAP 16384

typedef float f32x4 __attribute__((ext_vector_type(4)));
typedef float f32x8 __attribute__((ext_vector_type(8)));
typedef short bf16x8 __attribute__((ext_vector_type(8)));
typedef unsigned short ushort8 __attribute__((ext_vector_type(8)));
typedef unsigned short ushort16 __attribute__((ext_vector_type(16)));

__device__ __forceinline__ unsigned short f2bf(float f) {
    unsigned u = __builtin_bit_cast(unsigned, f);
    u += 0x7fffu + ((u >> 16) & 1u);
    return (unsigned short)(u >> 16);
}

__device__ __forceinline__ float bf2f(unsigned short u) {
    return __builtin_bit_cast(float, (unsigned)u << 16);
}

__device__ __forceinline__ void glds16(const void* g, void* l) {
    __builtin_amdgcn_global_load_lds((const __attribute__((address_space(1))) void*)g,
                                     (__attribute__((address_space(3))) void*)l, 16, 0, 0);
}

// ---------------- merged: routing | wg1 cast | hs cast ----------------
// bid 0:               routing + scan + tmap (first => tail hides under casts)
// bids [1, 12289):     gate_up -> wg1 pre-swizzled tiles   (2 chunks/thread)
// bids [12289, 16385): hidden_states fp32 -> bf16 linear   (16 floats/thread)
// (down_proj cast moved into gemm1's grid — gemm2 is the only consumer of wg2)
__global__ void cast_route_kernel(const float* __restrict__ gup, const float* __restrict__ hs,
                                  const int* __restrict__ tki, const float* __restrict__ tkw,
                                  unsigned short* __restrict__ wg1,
                                  unsigned short* __restrict__ hsb,
                                  int* __restrict__ counts, int* __restrict__ poffs,
                                  int* __restrict__ ntot, int* __restrict__ tmap,
                                  int* __restrict__ toks, float* __restrict__ wts) {
    const int bid = blockIdx.x;
    if (bid == 0) {
        __shared__ int lcnt[NE];
        const int tid = threadIdx.x;
        if (tid < NE) lcnt[tid] = 0;
        __syncthreads();
        for (int t = tid; t < TT; t += 256) {
            #pragma unroll
            for (int k = 0; k < TOPK; ++k) {
                int e = tki[t * TOPK + k];
                int p = atomicAdd(&lcnt[e], 1);
                toks[e * CAP + p] = t | (k << 15);
                wts[e * CAP + p] = tkw[t * TOPK + k];
            }
        }
        __syncthreads();
        if (tid == 0) {
            int s = 0, nt = 0;
            for (int e = 0; e < NE; ++e) {
                counts[e] = lcnt[e];
                poffs[e] = s;
                int ct = (lcnt[e] + 127) >> 7;
                for (int m = 0; m < ct; ++m) tmap[nt++] = e | (m << 8);
                s += ct << 7;
            }
            poffs[NE] = s;
            ntot[0] = nt;
        }
    } else if (bid < 12289) {
        size_t gid0 = (size_t)(bid - 1) * 512 + threadIdx.x * 2;   // even chunk index
        int sc = gid0 & 7;                 // even
        int r = (gid0 >> 3) & 255;
        int kt = (gid0 >> 11) & 31;
        int rest = (int)(gid0 >> 16);      // e*6 + it
        int it = rest % 6;
        int e = rest / 6;
        int grow = (r < 128) ? (it * 128 + r) : (II + it * 128 + (r - 128));
        const float* rp = &gup[((size_t)e * (2 * II) + grow) * HH + kt * 64];
        int c0 = sc ^ (r & 7), c1 = c0 ^ 1;
        const float4 a0 = *reinterpret_cast<const float4*>(rp + c0 * 8);
        const float4 a1 = *reinterpret_cast<const float4*>(rp + c0 * 8 + 4);
        const float4 b0 = *reinterpret_cast<const float4*>(rp + c1 * 8);
        const float4 b1 = *reinterpret_cast<const float4*>(rp + c1 * 8 + 4);
        ushort16 o;
        o[0] = f2bf(a0.x); o[1] = f2bf(a0.y); o[2]  = f2bf(a0.z); o[3]  = f2bf(a0.w);
        o[4] = f2bf(a1.x); o[5] = f2bf(a1.y); o[6]  = f2bf(a1.z); o[7]  = f2bf(a1.w);
        o[8] = f2bf(b0.x); o[9] = f2bf(b0.y); o[10] = f2bf(b0.z); o[11] = f2bf(b0.w);
        o[12] = f2bf(b1.x); o[13] = f2bf(b1.y); o[14] = f2bf(b1.z); o[15] = f2bf(b1.w);
        *reinterpret_cast<ushort16*>(&wg1[gid0 * 8]) = o;
    } else {
        size_t i0 = ((size_t)(bid - 12289) * 256 + threadIdx.x) * 4;  // float4 chunks
        const float4* src = reinterpret_cast<const float4*>(hs);
        const float4 v0 = src[i0], v1 = src[i0 + 1], v2 = src[i0 + 2], v3 = src[i0 + 3];
        ushort16 o;
        o[0] = f2bf(v0.x); o[1] = f2bf(v0.y); o[2]  = f2bf(v0.z); o[3]  = f2bf(v0.w);
        o[4] = f2bf(v1.x); o[5] = f2bf(v1.y); o[6]  = f2bf(v1.z); o[7]  = f2bf(v1.w);
        o[8] = f2bf(v2.x); o[9] = f2bf(v2.y); o[10] = f2bf(v2.z); o[11] = f2bf(v2.w);
        o[12] = f2bf(v3.x); o[13] = f2bf(v3.y); o[14] = f2bf(v3.z); o[15] = f2bf(v3.w);
        *reinterpret_cast<ushort16*>(&hsb[i0 * 4]) = o;
    }
}

// ---------------- GEMM1 (bids 0..863) + packed down_proj cast (bids 864..7007) ----
// gemm1 is latency-bound at 21% HBM; the appended cast blocks trail into CU
// slots freed by gemm1's uneven second dispatch round and soak the spare BW.
// wg2 is only read by gemm2 (next kernel), so no intra-kernel dependency.
__global__ __launch_bounds__(256, 2) void gemm1_kernel(
    const unsigned short* __restrict__ hsb, const unsigned short* __restrict__ wg1,
    const float* __restrict__ dwn, unsigned short* __restrict__ wg2,
    const int* __restrict__ counts, const int* __restrict__ poffs,
    const int* __restrict__ ntotp, const int* __restrict__ tmap,
    const int* __restrict__ toks, unsigned short* __restrict__ actT) {
    const int b = blockIdx.x;
    if (b >= 864) {
        // ---- down_proj fp32 -> bf16 pre-swizzled tiles (2 chunks/thread) ----
        size_t gid0 = (size_t)(b - 864) * 512 + threadIdx.x * 2;
        int sc = gid0 & 7;                 // even
        int r = (gid0 >> 3) & 127;
        int kt = (int)((gid0 >> 10) % 12);
        int rest = (int)(gid0 / (12 << 10));  // e*16 + ht
        int ht = rest & 15;
        int e = rest >> 4;
        int hrow = ht * 128 + r;
        const float* rp = &dwn[((size_t)e * HH + hrow) * II + kt * 64];
        int c0 = sc ^ (r & 7), c1 = c0 ^ 1;
        const float4 a0 = *reinterpret_cast<const float4*>(rp + c0 * 8);
        const float4 a1 = *reinterpret_cast<const float4*>(rp + c0 * 8 + 4);
        const float4 b0 = *reinterpret_cast<const float4*>(rp + c1 * 8);
        const float4 b1 = *reinterpret_cast<const float4*>(rp + c1 * 8 + 4);
        ushort16 o;
        o[0] = f2bf(a0.x); o[1] = f2bf(a0.y); o[2]  = f2bf(a0.z); o[3]  = f2bf(a0.w);
        o[4] = f2bf(a1.x); o[5] = f2bf(a1.y); o[6]  = f2bf(a1.z); o[7]  = f2bf(a1.w);
        o[8] = f2bf(b0.x); o[9] = f2bf(b0.y); o[10] = f2bf(b0.z); o[11] = f2bf(b0.w);
        o[12] = f2bf(b1.x); o[13] = f2bf(b1.y); o[14] = f2bf(b1.z); o[15] = f2bf(b1.w);
        *reinterpret_cast<ushort16*>(&wg2[gid0 * 8]) = o;
        return;
    }
    const int w = (b & 7) * 108 + (b >> 3);   // XCD-grouped
    const int ibt = w / 144;                  // i-tile 0..5
    const int gt = w % 144;
    if (gt >= ntotp[0]) return;
    const int ent = tmap[gt];
    const int e = ent & 255;
    const int mbase = (ent >> 8) << 7;
    const int cnt = counts[e];
    const int tid = threadIdx.x;
    const int lane = tid & 63;
    const int wid = tid >> 6;
    const int wm = wid >> 1, wn = wid & 1;

    __shared__ unsigned short sA[128 * 64];
    __shared__ unsigned short sB[256 * 64];
    __shared__ int s_tok[128];

    if (tid < 128) {
        int r = mbase + tid;
        s_tok[tid] = toks[e * CAP + ((r < cnt) ? r : (cnt - 1))] & 0x1FFF;
    }
    __syncthreads();

    size_t abase[4];
    #pragma unroll
    for (int it = 0; it < 4; ++it) {
        int idx = it * 256 + tid;
        int r = idx >> 3, sc = idx & 7;
        abase[it] = (size_t)s_tok[r] * HH + ((sc ^ (r & 7)) << 3);
    }
    const unsigned short* bbase = wg1 + ((size_t)(e * 6 + ibt) << 19) + (size_t)tid * 8;

    f32x4 accg[4][4], accu[4][4];
    #pragma unroll
    for (int m = 0; m < 4; ++m)
        #pragma unroll
        for (int n = 0; n < 4; ++n) {
            accg[m][n] = (f32x4){0.f, 0.f, 0.f, 0.f};
            accu[m][n] = (f32x4){0.f, 0.f, 0.f, 0.f};
        }

    const int lrow = lane & 15;
    const int lk8 = (lane >> 4) << 3;

    for (int k0 = 0; k0 < HH; k0 += 64) {
        #pragma unroll
        for (int it = 0; it < 4; ++it)
            glds16(hsb + abase[it] + k0, (char*)sA + it * 4096 + wid * 1024);
        const unsigned short* bk = bbase + ((size_t)(k0 >> 6) * 16384);
        #pragma unroll
        for (int it = 0; it < 8; ++it)
            glds16(bk + it * 2048, (char*)sB + it * 4096 + wid * 1024);
        __syncthreads();
        #pragma unroll
        for (int ks = 0; ks < 2; ++ks) {
            bf16x8 af[4], bg[4], bu[4];
            #pragma unroll
            for (int m = 0; m < 4; ++m) {
                int row = wm * 64 + m * 16 + lrow;
                af[m] = *reinterpret_cast<const bf16x8*>(
                    &sA[(row << 6) + ((ks * 32 + lk8) ^ ((row & 7) << 3))]);
            }
            #pragma unroll
            for (int n = 0; n < 4; ++n) {
                int rg = wn * 64 + n * 16 + lrow;
                bg[n] = *reinterpret_cast<const bf16x8*>(
                    &sB[(rg << 6) + ((ks * 32 + lk8) ^ ((rg & 7) << 3))]);
                int ru = rg + 128;
                bu[n] = *reinterpret_cast<const bf16x8*>(
                    &sB[(ru << 6) + ((ks * 32 + lk8) ^ ((ru & 7) << 3))]);
            }
            #pragma unroll
            for (int m = 0; m < 4; ++m)
                #pragma unroll
                for (int n = 0; n < 4; ++n) {
                    accg[m][n] = __builtin_amdgcn_mfma_f32_16x16x32_bf16(af[m], bg[n], accg[m][n], 0, 0, 0);
                    accu[m][n] = __builtin_amdgcn_mfma_f32_16x16x32_bf16(af[m], bu[n], accu[m][n], 0, 0, 0);
                }
        }
        __syncthreads();
    }

    // epilogue: SwiGLU -> actT swizzled [128][64] K-tiles
    const int mt = (poffs[e] + mbase) >> 7;
    #pragma unroll
    for (int m = 0; m < 4; ++m)
        #pragma unroll
        for (int n = 0; n < 4; ++n)
            #pragma unroll
            for (int j = 0; j < 4; ++j) {
                int row = wm * 64 + m * 16 + ((lane >> 4) << 2) + j;
                if (mbase + row < cnt) {
                    int c = wn * 64 + n * 16 + lrow;   // 0..127 within i-tile
                    int ktile = ibt * 2 + (c >> 6);
                    int cc = c & 63;
                    float g = accg[m][n][j], u = accu[m][n][j];
                    float a = (g / (1.f + __expf(-g))) * u;
                    actT[((size_t)(mt * 12 + ktile) * 128 + row) * 64 +
                         (((cc >> 3) ^ (row & 7)) << 3) + (cc & 7)] = f2bf(a);
                }
            }
}

// ---------------- GEMM2: partial[k][tok][h] = bf16( w * (actT . down^T) ) ----------------
__global__ __launch_bounds__(256) void gemm2_kernel(
    const unsigned short* __restrict__ actT, const unsigned short* __restrict__ wg2,
    const int* __restrict__ counts, const int* __restrict__ poffs,
    const int* __restrict__ ntotp, const int* __restrict__ tmap,
    const int* __restrict__ toks, const float* __restrict__ wts,
    unsigned short* __restrict__ partial) {
    const int b = blockIdx.x;                 // 2304 = 16*144
    const int w = (b & 7) * 288 + (b >> 3);   // XCD-grouped
    const int ht = w / 144;                   // h-tile 0..15
    const int gt = w % 144;
    if (gt >= ntotp[0]) return;
    const int ent = tmap[gt];
    const int e = ent & 255;
    const int mbase = (ent >> 8) << 7;
    const int cnt = counts[e];
    const int tid = threadIdx.x;
    const int lane = tid & 63;
    const int wid = tid >> 6;
    const int wm = wid >> 1, wn = wid & 1;

    __shared__ unsigned short sA[128 * 64];
    __shared__ unsigned short sB[128 * 64];
    __shared__ int s_tok[128];
    __shared__ float s_wt[128];

    if (tid < 128) {
        int r = mbase + tid;
        int rc = (r < cnt) ? r : (cnt - 1);
        s_tok[tid] = toks[e * CAP + rc];
        s_wt[tid] = wts[e * CAP + rc];
    }

    const int mt = (poffs[e] + mbase) >> 7;
    const unsigned short* abase = actT + (size_t)(mt * 12) * 8192 + (size_t)tid * 8;
    const unsigned short* bbase = wg2 + (size_t)((e * 16 + ht) * 12) * 8192 + (size_t)tid * 8;

    f32x4 acc[4][4];
    #pragma unroll
    for (int m = 0; m < 4; ++m)
        #pragma unroll
        for (int n = 0; n < 4; ++n) acc[m][n] = (f32x4){0.f, 0.f, 0.f, 0.f};

    const int lrow = lane & 15;
    const int lk8 = (lane >> 4) << 3;

    for (int kt = 0; kt < 12; ++kt) {
        #pragma unroll
        for (int it = 0; it < 4; ++it)
            glds16(abase + (size_t)kt * 8192 + it * 2048, (char*)sA + it * 4096 + wid * 1024);
        #pragma unroll
        for (int it = 0; it < 4; ++it)
            glds16(bbase + (size_t)kt * 8192 + it * 2048, (char*)sB + it * 4096 + wid * 1024);
        __syncthreads();
        #pragma unroll
        for (int ks = 0; ks < 2; ++ks) {
            bf16x8 af[4], bb[4];
            #pragma unroll
            for (int m = 0; m < 4; ++m) {
                int row = wm * 64 + m * 16 + lrow;
                af[m] = *reinterpret_cast<const bf16x8*>(
                    &sA[(row << 6) + ((ks * 32 + lk8) ^ ((row & 7) << 3))]);
            }
            #pragma unroll
            for (int n = 0; n < 4; ++n) {
                int rb = wn * 64 + n * 16 + lrow;
                bb[n] = *reinterpret_cast<const bf16x8*>(
                    &sB[(rb << 6) + ((ks * 32 + lk8) ^ ((rb & 7) << 3))]);
            }
            #pragma unroll
            for (int m = 0; m < 4; ++m)
                #pragma unroll
                for (int n = 0; n < 4; ++n)
                    acc[m][n] = __builtin_amdgcn_mfma_f32_16x16x32_bf16(af[m], bb[n], acc[m][n], 0, 0, 0);
        }
        __syncthreads();
    }

    // guarded epilogue: pad rows must NOT store (R4 lesson)
    #pragma unroll
    for (int m = 0; m < 4; ++m) {
        int row = wm * 64 + m * 16 + ((lane >> 4) << 2);
        #pragma unroll
        for (int j = 0; j < 4; ++j) {
            if (mbase + row + j < cnt) {
                int v = s_tok[row + j];
                size_t rbase = ((size_t)(v >> 15) * TT + (v & 0x1FFF)) * HH + ht * 128;
                float w = s_wt[row + j];
                #pragma unroll
                for (int n = 0; n < 4; ++n)
                    partial[rbase + wn * 64 + n * 16 + lrow] = f2bf(acc[m][n][j] * w);
            }
        }
    }
}

// ---------------- combine: out = partial[0] + partial[1] (bf16 -> fp32) ----------------
__global__ void combine_kernel(const unsigned short* __restrict__ partial, float* __restrict__ out) {
    size_t i = ((size_t)blockIdx.x * blockDim.x + threadIdx.x) * 2;  // two 8-chunks per thread
    const ushort8* pa = reinterpret_cast<const ushort8*>(partial);
    const ushort8* pb = reinterpret_cast<const ushort8*>(partial + (size_t)TT * HH);
    const ushort8 a0 = pa[i], a1 = pa[i + 1];
    const ushort8 b0 = pb[i], b1 = pb[i + 1];
    f32x8 o0, o1;
    #pragma unroll
    for (int j = 0; j < 8; ++j) { o0[j] = bf2f(a0[j]) + bf2f(b0[j]); o1[j] = bf2f(a1[j]) + bf2f(b1[j]); }
    *reinterpret_cast<f32x8*>(&out[i * 8]) = o0;
    *reinterpret_cast<f32x8*>(&out[i * 8 + 8]) = o1;
}

extern "C" void kernel_launch(void* const* d_in, const int* in_sizes, int n_in,
                              void* d_out, int out_size, void* d_ws, size_t ws_size,
                              hipStream_t stream) {
    const float* hs = (const float*)d_in[0];
    const int* tki = (const int*)d_in[1];
    const float* tkw = (const float*)d_in[2];
    const float* gup = (const float*)d_in[3];
    const float* dwn = (const float*)d_in[4];
    float* out = (float*)d_out;

    char* ws = (char*)d_ws;
    int* counts = (int*)(ws);                                     // [0,64)
    int* poffs = (int*)(ws + 128);                                // [128,196)
    int* ntot = (int*)(ws + 224);                                 // [224,228)
    int* tmap = (int*)(ws + 256);                                 // [256,896)
    int* toks = (int*)(ws + 1024);                                // 1 MB
    float* wts = (float*)(ws + 1024 + (size_t)CAP * NE * 4);      // 1 MB
    unsigned short* hsb = (unsigned short*)(ws + 2098176);        // 33.55 MB
    unsigned short* wg1 = (unsigned short*)(ws + 35652608);       // 100.66 MB
    unsigned short* wg2 = (unsigned short*)(ws + 136315904);      // 50.33 MB
    unsigned short* actT = (unsigned short*)(ws + 186647552);     // 28.31 MB
    // partial[2][TT][HH] bf16 = 67.1 MB overlays [hsb, wg1-head] — both dead
    // after gemm1 completes (stream-ordered before gemm2).
    unsigned short* partial = (unsigned short*)(ws + 2098176);

    cast_route_kernel<<<16385, 256, 0, stream>>>(gup, hs, tki, tkw, wg1, hsb,
                                                 counts, poffs, ntot, tmap, toks, wts);
    gemm1_kernel<<<7008, 256, 0, stream>>>(hsb, wg1, dwn, wg2,
                                           counts, poffs, ntot, tmap, toks, actT);
    gemm2_kernel<<<2304, 256, 0, stream>>>(actT, wg2, counts, poffs, ntot, tmap, toks, wts, partial);
    combine_kernel<<<(TT * HH / 16) / 256, 256, 0, stream>>>(partial, out);
}